// Round 7
// baseline (569.905 us; speedup 1.0000x reference)
//
#include <hip/hip_runtime.h>
#include <hip/hip_bf16.h>
#include <math.h>

// (B,T,D,H,O) = (1024, 512, 64, 64, 32)
#define BB 1024
#define TT 512
#define OO 32
#define MM 2               // batch rows per block
#define NBLK (BB/MM)       // 512 blocks -> 2 per CU (two independent chains)

typedef __attribute__((ext_vector_type(8))) short short8;   // 8 bf16 (4 VGPRs)
typedef __attribute__((ext_vector_type(4))) float f32x4;    // MFMA C/D

#define MFMA __builtin_amdgcn_mfma_f32_16x16x32_bf16
#define LOG2E 1.4426950408889634f
#define K2    2.8853900817779268f   /* 2*log2(e) */

// Raw barrier: waits LDS ops only; global loads stay in flight (no vmcnt drain).
#define BAR() asm volatile("s_waitcnt lgkmcnt(0)\n\ts_barrier" ::: "memory")

// raw v_exp_f32 (2^x)
__device__ __forceinline__ float exp2f_(float x) {
#if __has_builtin(__builtin_amdgcn_exp2f)
    return __builtin_amdgcn_exp2f(x);
#else
    float r; asm("v_exp_f32 %0, %1" : "=v"(r) : "v"(x)); return r;
#endif
}

// fp32 -> bf16 RNE (one-time weight conversion)
__device__ __forceinline__ ushort f2bf(float f) {
    union { float f; unsigned u; } v; v.f = f;
    unsigned r = v.u + 0x7FFF + ((v.u >> 16) & 1);
    return (ushort)(r >> 16);
}
__device__ __forceinline__ float bf2f(ushort u) {
    union { unsigned u; float f; } v; v.u = ((unsigned)u) << 16; return v.f;
}
// pack two fp32 -> bf16x2 via v_perm (round-half-up)
__device__ __forceinline__ unsigned pkbf(float a, float b) {
    union { float f; unsigned u; } x, y; x.f = a; y.f = b;
    return __builtin_amdgcn_perm(y.u + 0x8000u, x.u + 0x8000u, 0x07060302u);
}
__device__ __forceinline__ short8 pack8(const float4& a, const float4& b) {
    union { unsigned u[4]; short8 s; } r;
    r.u[0] = pkbf(a.x, a.y); r.u[1] = pkbf(a.z, a.w);
    r.u[2] = pkbf(b.x, b.y); r.u[3] = pkbf(b.z, b.w);
    return r.s;
}

// Fused 2-layer LSTM, 2 batch rows/block, 512 blocks (2 independent
// barrier-chains per CU). Block = 256 thr = 4 waves: waves 0-1 = layer 0
// cell(t), waves 2-3 = layer 1 cell(t-1) (lag-1 fusion). Each wave covers
// 128 gate cols (per gate g: cols 64g+32w..+31) with 32 B-frags in VGPRs.
// Batch rows are REPLICATED in the MFMA M dim (A row = l15&1), so every
// lane's C/D regs hold real rows: the lane's single cell (row=quad&1,
// unit=32w+16(quad>>1)+l15) is selected from its own regs via 3 cndmask
// per gate -- no LDS gate exchange, no extra latency. One barrier/step.
__global__ __launch_bounds__(256, 2)
void lstm_v7(const float* __restrict__ x,         // [B][T][64] fp32
             const float* __restrict__ w_ih0,     // [256][64]
             const float* __restrict__ w_hh0,     // [256][64]
             const float* __restrict__ b_ih0,     // [256]
             const float* __restrict__ b_hh0,     // [256]
             const float* __restrict__ w_ih1,     // [256][64]
             const float* __restrict__ w_hh1,     // [256][64]
             const float* __restrict__ b_ih1,     // [256]
             const float* __restrict__ b_hh1,     // [256]
             const float* __restrict__ fc_w,      // [32][64]
             const float* __restrict__ fc_b,      // [32]
             float* __restrict__ out)             // [B][32]
{
    // 2 rows only; stride 72 ushorts keeps 16B alignment for ds_read_b128
    __shared__ ushort h0s[2][MM][72];
    __shared__ ushort h1s[2][MM][72];

    const int tid  = threadIdx.x;
    const int wv   = tid >> 6;           // 0..3
    const bool gB  = (wv >= 2);          // layer-1 group
    const int w    = wv & 1;             // col-half within layer group
    const int ln   = tid & 63;
    const int l15  = ln & 15;
    const int quad = ln >> 4;
    const int b0   = blockIdx.x * MM;

    const bool qb0 = (quad & 1) != 0;    // cell row
    const bool qb1 = (quad & 2) != 0;    // cell n-tile
    const int  hrow = quad & 1;
    const int  hu   = 32 * w + 16 * (quad >> 1) + l15;   // cell unit col

    // ---- one-time: weights as B-frags (32 x short8), exp2-scales folded ----
    // B[k][n] frag (16x16x32): lane holds k = quad*8+j, n = l15.
    // K=128: k<64 -> input half (x or h0), k>=64 -> recurrent half.
    // gate order i,f,g,o; scale: i,f,o -> -log2e (e^-x), g -> +2log2e (e^2g).
    const float* wih = gB ? w_ih1 : w_ih0;
    const float* whh = gB ? w_hh1 : w_hh0;
    const float* bih = gB ? b_ih1 : b_ih0;
    const float* bhh = gB ? b_hh1 : b_hh0;

    short8 bfrag[4][2][4];               // [gate][ntile][ktile]
    float  bias_c[4];                    // this lane's cell bias per gate
#pragma unroll
    for (int g = 0; g < 4; ++g) {
        const float sc = (g == 2) ? K2 : -LOG2E;
        bias_c[g] = (bih[64 * g + hu] + bhh[64 * g + hu]) * sc;
#pragma unroll
        for (int n = 0; n < 2; ++n) {
            const int col = 64 * g + 32 * w + 16 * n + l15;
#pragma unroll
            for (int kt = 0; kt < 4; ++kt) {
                const int kb = kt * 32 + quad * 8;
                const float* src = (kb < 64) ? (wih + col * 64 + kb)
                                             : (whh + col * 64 + (kb - 64));
                const float4 v0 = *(const float4*)src;
                const float4 v1 = *(const float4*)(src + 4);
                short8 b;
                b[0] = (short)f2bf(v0.x * sc); b[1] = (short)f2bf(v0.y * sc);
                b[2] = (short)f2bf(v0.z * sc); b[3] = (short)f2bf(v0.w * sc);
                b[4] = (short)f2bf(v1.x * sc); b[5] = (short)f2bf(v1.y * sc);
                b[6] = (short)f2bf(v1.z * sc); b[7] = (short)f2bf(v1.w * sc);
                bfrag[g][n][kt] = b;
            }
        }
    }

    // x A-frag base (L0 waves): replicated row = l15&1, k = quad*8..+7 (+32)
    const size_t xoff = ((size_t)(b0 + (l15 & 1)) * TT) * 64 + quad * 8;
    float4 xfA0, xfA1, xfA2, xfA3, xfB0, xfB1, xfB2, xfB3;

#define ISSUE(t_, S)                                                          \
    if ((t_) < TT) {                                                          \
        const float* p = x + xoff + (size_t)(t_) * 64;                        \
        xf##S##0 = *(const float4*)p;        xf##S##1 = *(const float4*)(p + 4);  \
        xf##S##2 = *(const float4*)(p + 32); xf##S##3 = *(const float4*)(p + 36); \
    }

    // zero both h double-buffers
    for (int i = tid; i < 2 * MM * 72; i += 256) {
        ((ushort*)h0s)[i] = 0;
        ((ushort*)h1s)[i] = 0;
    }
    if (!gB) { ISSUE(0, A); ISSUE(1, B); }

    const f32x4 z4 = {0.f, 0.f, 0.f, 0.f};
    float cc = 0.f;                      // this lane's single cell state
    BAR();

// gate select from own regs (row-replication makes all quads hold real rows):
// value for (row=quad&1, ntile=quad>>1) = acc[g][quad>>1][quad&1]
#define YSEL(g) ((qb1 ? (qb0 ? acc[g][1][1] : acc[g][1][0])                   \
                      : (qb0 ? acc[g][0][1] : acc[g][0][0])) + bias_c[g])

// cell: 5 exp2 + 3 rcp, overflow-clamped; writes h (bf16) to HD[NXT]
#define CELL(HD, NXT)                                                         \
    {                                                                         \
        const float yi = YSEL(0), yf = YSEL(1);                               \
        const float yg = YSEL(2), yo = YSEL(3);                               \
        const float Ef = exp2f_(yf);                                          \
        const float Ei = exp2f_(yi);                                          \
        const float Eg = exp2f_(fminf(yg, 80.f));                             \
        const float sf = __builtin_amdgcn_rcpf(1.f + Ef);                     \
        const float rd = __builtin_amdgcn_rcpf((1.f + Ei) * (1.f + Eg));      \
        cc = sf * cc + (Eg - 1.f) * rd;                                       \
        const float Ec = exp2f_(fminf(cc * K2, 80.f));                        \
        const float Eo = exp2f_(yo);                                          \
        const float r2 = __builtin_amdgcn_rcpf((1.f + Eo) * (1.f + Ec));      \
        union { float f; unsigned uu; } hv; hv.f = (Ec - 1.f) * r2;           \
        HD[NXT][hrow][hu] = (ushort)((hv.uu + 0x8000u) >> 16);                \
    }

// step t_: L0 cell(t_) if DOA (x slot S), L1 cell(t_-1) if DOB.
#define STEP(t_, CUR, NXT, S, DOA, DOB)                                       \
    {                                                                         \
        if (!gB) {                                                            \
            if (DOA) {                                                        \
                const short8 a2 = *(const short8*)&h0s[CUR][l15 & 1][quad * 8];      \
                const short8 a3 = *(const short8*)&h0s[CUR][l15 & 1][32 + quad * 8]; \
                const short8 xlo = pack8(xf##S##0, xf##S##1);                 \
                const short8 xhi = pack8(xf##S##2, xf##S##3);                 \
                ISSUE((t_) + 2, S);                                           \
                f32x4 acc[4][2];                                              \
                _Pragma("unroll")                                             \
                for (int g = 0; g < 4; ++g) {                                 \
                    _Pragma("unroll")                                         \
                    for (int n = 0; n < 2; ++n)                               \
                        acc[g][n] =                                           \
                          MFMA(a3, bfrag[g][n][3],                            \
                          MFMA(a2, bfrag[g][n][2],                            \
                          MFMA(xhi, bfrag[g][n][1],                           \
                          MFMA(xlo, bfrag[g][n][0], z4, 0,0,0), 0,0,0), 0,0,0), 0,0,0); \
                }                                                             \
                CELL(h0s, NXT);                                               \
            }                                                                 \
        } else {                                                              \
            if (DOB) {                                                        \
                const short8 a0 = *(const short8*)&h0s[CUR][l15 & 1][quad * 8];      \
                const short8 a1 = *(const short8*)&h0s[CUR][l15 & 1][32 + quad * 8]; \
                const short8 a2 = *(const short8*)&h1s[CUR][l15 & 1][quad * 8];      \
                const short8 a3 = *(const short8*)&h1s[CUR][l15 & 1][32 + quad * 8]; \
                f32x4 acc[4][2];                                              \
                _Pragma("unroll")                                             \
                for (int g = 0; g < 4; ++g) {                                 \
                    _Pragma("unroll")                                         \
                    for (int n = 0; n < 2; ++n)                               \
                        acc[g][n] =                                           \
                          MFMA(a3, bfrag[g][n][3],                            \
                          MFMA(a2, bfrag[g][n][2],                            \
                          MFMA(a1, bfrag[g][n][1],                            \
                          MFMA(a0, bfrag[g][n][0], z4, 0,0,0), 0,0,0), 0,0,0), 0,0,0); \
                }                                                             \
                CELL(h1s, NXT);                                               \
            }                                                                 \
        }                                                                     \
        BAR();                                                                \
    }

    // head: L0(0) only
    STEP(0, 0, 1, A, 1, 0)
    // main: t = 1..510
    for (int tb = 1; tb + 2 < TT; tb += 2) {
        STEP(tb,     1, 0, B, 1, 1)
        STEP(tb + 1, 0, 1, A, 1, 1)
    }
    // t = 511: L0(511) + L1(510)
    STEP(TT - 1, 1, 0, B, 1, 1)
    // tail t = 512: L1(511) only -> h1s[1]
    STEP(TT, 0, 1, A, 0, 1)
#undef STEP
#undef CELL
#undef YSEL
#undef ISSUE

    // FC + softplus on h1(T-1) (h1s[1], rows 0-1); 64 outputs
    if (tid < MM * OO) {
        const int row = tid >> 5, o = tid & 31;
        float a = fc_b[o];
#pragma unroll
        for (int j = 0; j < 64; ++j)
            a = fmaf(fc_w[o * 64 + j], bf2f(h1s[1][row][j]), a);
        out[(size_t)(b0 + row) * OO + o] =
            fmaxf(a, 0.0f) + log1pf(__expf(-fabsf(a)));   // stable softplus
    }
}

extern "C" void kernel_launch(void* const* d_in, const int* in_sizes, int n_in,
                              void* d_out, int out_size, void* d_ws, size_t ws_size,
                              hipStream_t stream) {
    const float* x     = (const float*)d_in[0];
    const float* w_ih0 = (const float*)d_in[1];
    const float* w_hh0 = (const float*)d_in[2];
    const float* b_ih0 = (const float*)d_in[3];
    const float* b_hh0 = (const float*)d_in[4];
    const float* w_ih1 = (const float*)d_in[5];
    const float* w_hh1 = (const float*)d_in[6];
    const float* b_ih1 = (const float*)d_in[7];
    const float* b_hh1 = (const float*)d_in[8];
    const float* fc_w  = (const float*)d_in[9];
    const float* fc_b  = (const float*)d_in[10];
    float* out = (float*)d_out;

    lstm_v7<<<dim3(NBLK), dim3(256), 0, stream>>>(
        x, w_ih0, w_hh0, b_ih0, b_hh0,
        w_ih1, w_hh1, b_ih1, b_hh1, fc_w, fc_b, out);
}